// Round 6
// baseline (509.130 us; speedup 1.0000x reference)
//
#include <hip/hip_runtime.h>
#include <math.h>

// ---------------------------------------------------------------------------
// EncoderGPECls: kNN(16) -> PCA curvature blend -> adaptive GPE embeddings
// xyz: [8,4096,3] f32  ->  out: [8,4096,128] f32
//
// R6: x-sorted windowed kNN.
//   presort_kernel: per-batch bitonic sort by x (order-preserving bits) ->
//     sorted float4 (x,y,z,orig_idx) in ws; also per-batch double stats.
//   knn_kernel: 128-thr blocks, wave = 64 x-contiguous queries; scan
//     64-candidate chunks outward; direction closes when __all(gap^2>=maxv)
//     (exact: sorted x => d2 >= gap^2). ONE stream per query (no candidate
//     split -> ~3x less insert work than R5), transposed conflict-free
//     append buffers (bank = tid mod 32 regardless of per-lane cnt).
//   finalize restored to its own 1-block kernel (R5 folded it into all 16384
//     out-blocks serially on thread 0 -> was ~80us of hidden tail).
//
// ws float layout:
//   [0, 32768)            curv per point
//   [32768, 131072)       rasig2 (3 SoA planes of 32768)
//   [131072, 131080)      curv batch sums (atomic, zeroed via memsetAsync)
//   [131080, 131176)      per-batch raw sums as 48 DOUBLES
//   [131176, 131180)      scalars: rasig1, blend, 1-blend
//   [131184, 262256)      sorted float4 per batch: 8 * 4096 * 4
// ---------------------------------------------------------------------------

#define NPTS 4096
#define KNN 17          // 16 neighbors + self (self contributes zero to sums)
#define CAP 8           // append slots per lane (transposed layout)
#define BLKT 128        // 2 waves; 64 queries per wave

#define WS_CURV  0
#define WS_RAS2  32768
#define WS_CSUM  131072
#define WS_STAT  131080
#define WS_SCAL  131176
#define WS_SORT  131184

typedef unsigned long long ull;

// predicated replace-max insert of (value, sorted-rank) into top-KNN
__device__ __forceinline__ void insertvi(float v, int ix, bool ins,
                                         float (&md)[KNN], int (&mr)[KNN],
                                         float& maxv, int& maxp) {
#pragma unroll
    for (int k = 0; k < KNN; k++) {
        bool sel = ins && (k == maxp);
        md[k] = sel ? v : md[k];
        mr[k] = sel ? ix : mr[k];
    }
    maxv = md[0]; maxp = 0;
#pragma unroll
    for (int k = 1; k < KNN; k++) {
        bool g = md[k] > maxv;
        maxv = g ? md[k] : maxv;
        maxp = g ? k : maxp;
    }
}

__device__ __forceinline__ void drain(float* vbuf, int* ibuf, int tid, int& cnt,
                                      float (&md)[KNN], int (&mr)[KNN],
                                      float& maxv, int& maxp) {
#pragma unroll
    for (int t = 0; t < CAP; t++) {
        if (__any(t < cnt)) {
            float d = vbuf[t * BLKT + tid];
            int ix = ibuf[t * BLKT + tid];
            bool ins = (t < cnt) && (d < maxv);
            if (__any(ins)) insertvi(d, ix, ins, md, mr, maxv, maxp);
        }
    }
    cnt = 0;
}

// scan one 64-candidate chunk (sorted ranks [c*64, c*64+64))
__device__ __forceinline__ void scanchunk(const float4* pts, int c, float4 qp,
                                          float* vbuf, int* ibuf, int tid, int& cnt,
                                          float (&md)[KNN], int (&mr)[KNN],
                                          float& maxv, int& maxp) {
    int base = c * 64;
    float4 cc[4];
#pragma unroll
    for (int u = 0; u < 4; u++) cc[u] = pts[base + u];
    for (int m = 0; m < 64; m += 4) {
        float4 cu[4];
#pragma unroll
        for (int u = 0; u < 4; u++) cu[u] = cc[u];
        int nb = base + ((m + 4) & 63);          // last prefetch wraps (redundant)
#pragma unroll
        for (int u = 0; u < 4; u++) cc[u] = pts[nb + u];
#pragma unroll
        for (int u = 0; u < 4; u++) {
            float4 ca = cu[u];
            float dx = qp.x - ca.x, dy = qp.y - ca.y, dz = qp.z - ca.z;
            float d2 = dx * dx + dy * dy + dz * dz;   // self: exactly +0, kept
            if (d2 < maxv) {
                vbuf[cnt * BLKT + tid] = d2;
                ibuf[cnt * BLKT + tid] = base + m + u;
                cnt++;
            }
        }
        if (__any(cnt > CAP - 4)) drain(vbuf, ibuf, tid, cnt, md, mr, maxv, maxp);
    }
    drain(vbuf, ibuf, tid, cnt, md, mr, maxv, maxp);  // sharpen maxv for bounds
}

// ---------------- presort: per-batch bitonic by x + double stats -----------
__global__ __launch_bounds__(512) void presort_kernel(const float* __restrict__ xyz,
                                                      float* __restrict__ ws) {
    __shared__ ull keys[NPTS];                   // 32 KB
    __shared__ double dst[48];
    int b = blockIdx.x;
    int tid = threadIdx.x;
    const float* base = xyz + b * NPTS * 3;

    // stats (double)
    double sx = 0, sy = 0, sz = 0, qxx = 0, qyy = 0, qzz = 0;
    for (int p = tid; p < NPTS; p += 512) {
        double x = (double)base[p * 3], y = (double)base[p * 3 + 1], z = (double)base[p * 3 + 2];
        sx += x; sy += y; sz += z; qxx += x * x; qyy += y * y; qzz += z * z;
    }
    for (int off = 32; off > 0; off >>= 1) {
        sx += __shfl_down(sx, off);  sy += __shfl_down(sy, off);
        sz += __shfl_down(sz, off);  qxx += __shfl_down(qxx, off);
        qyy += __shfl_down(qyy, off); qzz += __shfl_down(qzz, off);
    }
    int wid = tid >> 6;
    if ((tid & 63) == 0) {
        dst[wid * 6 + 0] = sx;  dst[wid * 6 + 1] = sy;  dst[wid * 6 + 2] = sz;
        dst[wid * 6 + 3] = qxx; dst[wid * 6 + 4] = qyy; dst[wid * 6 + 5] = qzz;
    }
    __syncthreads();
    if (tid == 0) {
        double* wd = (double*)(ws + WS_STAT);
        for (int q = 0; q < 6; q++) {
            double a = 0.0;
            for (int w = 0; w < 8; w++) a += dst[w * 6 + q];
            wd[b * 6 + q] = a;
        }
    }

    // keys: order-preserving uint of x, payload = orig idx
    for (int r = tid; r < NPTS; r += 512) {
        unsigned u = __float_as_uint(base[r * 3]);
        u = (u >> 31) ? ~u : (u | 0x80000000u);
        keys[r] = ((ull)u << 32) | (unsigned)r;
    }
    __syncthreads();

    // bitonic sort ascending
    for (int k = 2; k <= NPTS; k <<= 1) {
        for (int j = k >> 1; j > 0; j >>= 1) {
            for (int i = tid; i < NPTS; i += 512) {
                int l = i ^ j;
                if (l > i) {
                    ull a = keys[i], c = keys[l];
                    bool up = ((i & k) == 0);
                    if ((a > c) == up) { keys[i] = c; keys[l] = a; }
                }
            }
            __syncthreads();
        }
    }

    // gather coords -> sorted float4 (x,y,z, idx bits)
    float4* out4 = (float4*)(ws + WS_SORT) + b * NPTS;
    for (int r = tid; r < NPTS; r += 512) {
        int i = (int)(keys[r] & 0xffffffffULL);
        const float* pp = base + 3 * i;
        out4[r] = make_float4(pp[0], pp[1], pp[2], __int_as_float(i));
    }
}

// ---------------- gstd -> rasig1, blend ------------------------------------
__global__ void finalize_kernel(float* __restrict__ ws) {
    if (threadIdx.x == 0 && blockIdx.x == 0) {
        const double* st = (const double*)(ws + WS_STAT);
        double g = 0.0;
        for (int b = 0; b < 8; b++) {
            for (int d = 0; d < 3; d++) {
                double s = st[b * 6 + d], ss = st[b * 6 + 3 + d];
                double var = (ss - s * s / 4096.0) / 4095.0;
                g += sqrt(var > 0.0 ? var : 0.0);
            }
        }
        g *= (1.0 / 24.0);
        float gf = (float)g;
        float denom = 0.3f * (1.0f + gf) + 1e-6f;
        float blend = (float)(1.0 / (1.0 + exp(-((double)gf - 0.1) * 10.0)));
        ws[WS_SCAL + 0] = (float)(1.0 / (double)denom);
        ws[WS_SCAL + 1] = blend;
        ws[WS_SCAL + 2] = 1.0f - blend;
    }
}

// ---------------- 3x3 symmetric eigensolve (double, trig method) -----------
__device__ __forceinline__ float curv_from_cov(float c00, float c01, float c02,
                                               float c11, float c12, float c22) {
    double a00 = c00, a01 = c01, a02 = c02, a11 = c11, a12 = c12, a22 = c22;
    double tr = a00 + a11 + a22;
    double q  = tr * (1.0 / 3.0);
    double b00 = a00 - q, b11 = a11 - q, b22 = a22 - q;
    double p2 = b00 * b00 + b11 * b11 + b22 * b22
              + 2.0 * (a01 * a01 + a02 * a02 + a12 * a12);
    double lmin;
    if (p2 < 1e-60) {
        lmin = q;
    } else {
        double p  = sqrt(p2 * (1.0 / 6.0));
        double ip = 1.0 / p;
        double m00 = b00 * ip, m11 = b11 * ip, m22 = b22 * ip;
        double m01 = a01 * ip, m02 = a02 * ip, m12 = a12 * ip;
        double det = m00 * (m11 * m22 - m12 * m12)
                   - m01 * (m01 * m22 - m12 * m02)
                   + m02 * (m01 * m12 - m11 * m02);
        double r = 0.5 * det;
        r = r > 1.0 ? 1.0 : (r < -1.0 ? -1.0 : r);
        double phi = acos(r) * (1.0 / 3.0);
        lmin = q + 2.0 * p * cos(phi + 2.0943951023931953);
    }
    return (float)(lmin / (tr + 1e-6));
}

// ---------------- kNN + covariance + curvature + lstd ----------------------
__global__ __launch_bounds__(BLKT) void knn_kernel(float* __restrict__ ws) {
    __shared__ float4 pts[NPTS];                 // 64 KB (sorted by x)
    __shared__ float vbuf[CAP * BLKT];           // 4 KB, transposed slots
    __shared__ int   ibuf[CAP * BLKT];           // 2 KB... (CAP*128*4 = 4 KB)
    int b = blockIdx.x >> 5;                     // 32 blocks per batch
    int cblk = blockIdx.x & 31;
    int tid = threadIdx.x;
    const float4* sorted = (const float4*)(ws + WS_SORT) + b * NPTS;
    for (int p = tid; p < NPTS; p += BLKT) pts[p] = sorted[p];
    __syncthreads();

    int wv = tid >> 6, lane = tid & 63;
    int qrank = cblk * 128 + wv * 64 + lane;     // this lane's query (sorted rank)
    float4 qp = pts[qrank];
    int qorig = __float_as_int(qp.w);

    float md[KNN]; int mr[KNN];
#pragma unroll
    for (int k = 0; k < KNN; k++) { md[k] = 3.4e38f; mr[k] = 0; }
    float maxv = 3.4e38f; int maxp = 0; int cnt = 0;

    int c0 = qrank >> 6;                         // own chunk (wave-uniform)
    scanchunk(pts, c0, qp, vbuf, ibuf, tid, cnt, md, mr, maxv, maxp);

    int cr = c0 + 1, cl = c0 - 1;
    bool openR = cr < 64, openL = cl >= 0;
    float xq = qp.x;
    while (openR || openL) {
        if (openR) {
            float dx = pts[cr * 64].x - xq;      // >= 0 (sorted)
            if (__all(dx * dx >= maxv)) {
                openR = false;                   // all unscanned right: d2>=gap^2>=maxv
            } else {
                scanchunk(pts, cr, qp, vbuf, ibuf, tid, cnt, md, mr, maxv, maxp);
                cr++; openR = cr < 64;
            }
        }
        if (openL) {
            float dx = xq - pts[cl * 64 + 63].x; // >= 0 (sorted)
            if (__all(dx * dx >= maxv)) {
                openL = false;
            } else {
                scanchunk(pts, cl, qp, vbuf, ibuf, tid, cnt, md, mr, maxv, maxp);
                cl--; openL = cl >= 0;
            }
        }
    }

    // ---- epilogue (every lane): moments over the 17-set -> curv, rasig2 ----
    float s1x = 0, s1y = 0, s1z = 0;
    float cxx = 0, cxy = 0, cxz = 0, cyy = 0, cyz = 0, czz = 0;
#pragma unroll
    for (int k = 0; k < KNN; k++) {
        float4 c = pts[mr[k]];
        float ux = c.x - qp.x, uy = c.y - qp.y, uz = c.z - qp.z;
        s1x += ux; s1y += uy; s1z += uz;
        cxx += ux * ux; cxy += ux * uy; cxz += ux * uz;
        cyy += uy * uy; cyz += uy * uz; czz += uz * uz;
    }
    const float i16 = 1.0f / 16.0f, i15 = 1.0f / 15.0f;
    float mx = s1x * i16, my = s1y * i16, mz = s1z * i16;
    float c00 = (cxx - 16.0f * mx * mx) * i15;
    float c01 = (cxy - 16.0f * mx * my) * i15;
    float c02 = (cxz - 16.0f * mx * mz) * i15;
    float c11 = (cyy - 16.0f * my * my) * i15;
    float c12 = (cyz - 16.0f * my * mz) * i15;
    float c22 = (czz - 16.0f * mz * mz) * i15;

    float curv = curv_from_cov(c00, c01, c02, c11, c12, c22);

    float v0 = c00 > 0.0f ? c00 : 0.0f;
    float v1 = c11 > 0.0f ? c11 : 0.0f;
    float v2 = c22 > 0.0f ? c22 : 0.0f;
    float r2x = 1.0f / (0.3f * (1.0f + sqrtf(v0)) + 1e-6f);
    float r2y = 1.0f / (0.3f * (1.0f + sqrtf(v1)) + 1e-6f);
    float r2z = 1.0f / (0.3f * (1.0f + sqrtf(v2)) + 1e-6f);

    int g = b * NPTS + qorig;
    ws[WS_CURV + g] = curv;
    ws[WS_RAS2 + 0 * 32768 + g] = r2x;
    ws[WS_RAS2 + 1 * 32768 + g] = r2y;
    ws[WS_RAS2 + 2 * 32768 + g] = r2z;

    float cs = curv;
    for (int off = 32; off > 0; off >>= 1) cs += __shfl_down(cs, off);
    if (lane == 0) atomicAdd(&ws[WS_CSUM + b], cs);
}

// ---------------- final embedding ------------------------------------------
__global__ void out_kernel(const float* __restrict__ xyz,
                           const float* __restrict__ ws,
                           float* __restrict__ out) {
    int idx = blockIdx.x * 256 + (int)threadIdx.x;
    int j = idx & 127;
    int g = idx >> 7;
    int b = g >> 12;
    int f = (j < 127) ? j : 128;                      // OUT_IDX
    int d = (f >= 86) ? 2 : ((f >= 43) ? 1 : 0);
    int t = f - d * 43;
    float fv = (float)((double)(t + 1) * (2.0 / 44.0) - 1.0);  // FEAT_VAL[t]

    float x = xyz[g * 3 + d];
    float rasig1 = ws[WS_SCAL + 0];
    float blend  = ws[WS_SCAL + 1];
    float blendc = ws[WS_SCAL + 2];
    float cmean  = ws[WS_CSUM + b] * (1.0f / 4096.0f);
    float curv   = ws[WS_CURV + g];
    float w = 1.0f / (1.0f + __expf(-10.0f * (curv - cmean)));

    float t1 = (x - fv) * rasig1;
    float e1 = blend * __expf(-0.5f * t1 * t1) + blendc * __cosf(t1);
    float t2 = (x - fv) * ws[WS_RAS2 + (d << 15) + g];
    float e2 = __expf(-0.5f * t2 * t2);
    out[idx] = w * e1 + (1.0f - w) * e2;
}

extern "C" void kernel_launch(void* const* d_in, const int* in_sizes, int n_in,
                              void* d_out, int out_size, void* d_ws, size_t ws_size,
                              hipStream_t stream) {
    const float* xyz = (const float*)d_in[0];
    float* out = (float*)d_out;
    float* ws = (float*)d_ws;

    hipMemsetAsync(ws + WS_CSUM, 0, 8 * sizeof(float), stream);
    presort_kernel<<<8, 512, 0, stream>>>(xyz, ws);
    finalize_kernel<<<1, 64, 0, stream>>>(ws);
    knn_kernel<<<256, BLKT, 0, stream>>>(ws);
    out_kernel<<<out_size / 256, 256, 0, stream>>>(xyz, ws, out);
}

// Round 7
// 278.553 us; speedup vs baseline: 1.8278x; 1.8278x over previous
//
#include <hip/hip_runtime.h>
#include <math.h>

// ---------------------------------------------------------------------------
// EncoderGPECls: kNN(16) -> PCA curvature blend -> adaptive GPE embeddings
// xyz: [8,4096,3] f32  ->  out: [8,4096,128] f32
//
// R7 = R5 (query-per-lane, candidate-quarter-per-wave, broadcast LDS reads,
//          8 waves/CU) with the two diagnosed losses fixed:
//   (a) TRANSPOSED append buffers vbuf/ibuf[slot*256+tid]: stride 256 == 0
//       mod 32 -> bank = tid mod 32 regardless of per-lane cnt; worst case
//       2-way (free). R5's abuf[tid*CAP] had 64B lane stride -> 9.1e6
//       conflicts; R6 measured the transposed form at 108k.
//   (b) SEED the top-17 list directly from the quarter's first 17 candidates
//       (plain writes + one max-scan) -> kills the cold-start insert flood.
//   finalize_kernel stays separate (R5 folded it serially into 16384
//   out-blocks -> ~80us hidden tail, fixed in R6).
//
// ws float layout:
//   [0, 32768)            curv per point
//   [32768, 131072)       rasig2 (3 SoA planes of 32768)
//   [131072, 131080)      curv batch sums (atomic, zeroed via memsetAsync)
//   [131080, 131176)      per-batch raw sums as 48 DOUBLES
//   [131176, 131180)      scalars: rasig1, blend, 1-blend
// ---------------------------------------------------------------------------

#define NPTS 4096
#define KNN 17          // 16 neighbors + self (self contributes zero to sums)
#define CAP 8           // append slots per lane (transposed layout)
#define BLKT 256        // 4 waves; 64 queries per block (1 per lane)
#define QPB 64

#define WS_CURV  0
#define WS_RAS2  32768
#define WS_CSUM  131072
#define WS_STAT  131080
#define WS_SCAL  131176

// predicated replace-max insert of (value, index) into top-KNN
__device__ __forceinline__ void insertvi(float v, int ix, bool ins,
                                         float (&md)[KNN], int (&mi)[KNN],
                                         float& maxv, int& maxp) {
#pragma unroll
    for (int k = 0; k < KNN; k++) {
        bool sel = ins && (k == maxp);
        md[k] = sel ? v : md[k];
        mi[k] = sel ? ix : mi[k];
    }
    maxv = md[0]; maxp = 0;
#pragma unroll
    for (int k = 1; k < KNN; k++) {
        bool g = md[k] > maxv;
        maxv = g ? md[k] : maxv;
        maxp = g ? k : maxp;
    }
}

// drain transposed append buffers into top-KNN
__device__ __forceinline__ void drain(float* vbuf, int* ibuf, int tid, int& cnt,
                                      float (&md)[KNN], int (&mi)[KNN],
                                      float& maxv, int& maxp) {
#pragma unroll
    for (int t = 0; t < CAP; t++) {
        if (__any(t < cnt)) {
            float d = vbuf[t * BLKT + tid];
            int ix = ibuf[t * BLKT + tid];
            bool ins = (t < cnt) && (d < maxv);
            if (__any(ins)) insertvi(d, ix, ins, md, mi, maxv, maxp);
        }
    }
    cnt = 0;
}

// ---------------- gstd -> rasig1, blend ------------------------------------
__global__ void finalize_kernel(float* __restrict__ ws) {
    if (threadIdx.x == 0 && blockIdx.x == 0) {
        const double* st = (const double*)(ws + WS_STAT);
        double g = 0.0;
        for (int b = 0; b < 8; b++) {
            for (int d = 0; d < 3; d++) {
                double s = st[b * 6 + d], ss = st[b * 6 + 3 + d];
                double var = (ss - s * s / 4096.0) / 4095.0;
                g += sqrt(var > 0.0 ? var : 0.0);
            }
        }
        g *= (1.0 / 24.0);
        float gf = (float)g;
        float denom = 0.3f * (1.0f + gf) + 1e-6f;
        float blend = (float)(1.0 / (1.0 + exp(-((double)gf - 0.1) * 10.0)));
        ws[WS_SCAL + 0] = (float)(1.0 / (double)denom);
        ws[WS_SCAL + 1] = blend;
        ws[WS_SCAL + 2] = 1.0f - blend;
    }
}

// ---------------- 3x3 symmetric eigensolve (double, trig method) -----------
__device__ __forceinline__ float curv_from_cov(float c00, float c01, float c02,
                                               float c11, float c12, float c22) {
    double a00 = c00, a01 = c01, a02 = c02, a11 = c11, a12 = c12, a22 = c22;
    double tr = a00 + a11 + a22;
    double q  = tr * (1.0 / 3.0);
    double b00 = a00 - q, b11 = a11 - q, b22 = a22 - q;
    double p2 = b00 * b00 + b11 * b11 + b22 * b22
              + 2.0 * (a01 * a01 + a02 * a02 + a12 * a12);
    double lmin;
    if (p2 < 1e-60) {
        lmin = q;
    } else {
        double p  = sqrt(p2 * (1.0 / 6.0));
        double ip = 1.0 / p;
        double m00 = b00 * ip, m11 = b11 * ip, m22 = b22 * ip;
        double m01 = a01 * ip, m02 = a02 * ip, m12 = a12 * ip;
        double det = m00 * (m11 * m22 - m12 * m12)
                   - m01 * (m01 * m22 - m12 * m02)
                   + m02 * (m01 * m12 - m11 * m02);
        double r = 0.5 * det;
        r = r > 1.0 ? 1.0 : (r < -1.0 ? -1.0 : r);
        double phi = acos(r) * (1.0 / 3.0);
        lmin = q + 2.0 * p * cos(phi + 2.0943951023931953);
    }
    return (float)(lmin / (tr + 1e-6));
}

// ---------------- kNN + covariance + curvature + lstd ----------------------
__global__ __launch_bounds__(BLKT, 2) void knn_kernel(const float* __restrict__ xyz,
                                                      float* __restrict__ ws) {
    __shared__ float4 pts[NPTS];                 // 64 KB
    __shared__ float vbuf[CAP * BLKT];           // 8 KB, transposed slots
    __shared__ int   ibuf[CAP * BLKT];           // 8 KB, transposed slots
    int b = blockIdx.x >> 6;                     // 64 blocks per batch
    int chunk = blockIdx.x & 63;
    int tid = threadIdx.x;
    const float* base = xyz + b * NPTS * 3;
    for (int p = tid; p < NPTS; p += BLKT) {
        pts[p] = make_float4(base[p * 3], base[p * 3 + 1], base[p * 3 + 2], 0.0f);
    }
    __syncthreads();

    // ---- chunk-0 block computes per-batch raw sums in double (into ibuf) ----
    if (chunk == 0) {
        double sx = 0, sy = 0, sz = 0, qxx = 0, qyy = 0, qzz = 0;
        for (int p = tid; p < NPTS; p += BLKT) {
            float4 c = pts[p];
            sx += (double)c.x; sy += (double)c.y; sz += (double)c.z;
            qxx += (double)c.x * c.x; qyy += (double)c.y * c.y; qzz += (double)c.z * c.z;
        }
        for (int off = 32; off > 0; off >>= 1) {
            sx += __shfl_down(sx, off);  sy += __shfl_down(sy, off);
            sz += __shfl_down(sz, off);  qxx += __shfl_down(qxx, off);
            qyy += __shfl_down(qyy, off); qzz += __shfl_down(qzz, off);
        }
        double* dstat = (double*)ibuf;           // 384 B of the 8 KB
        int wid = tid >> 6;
        if ((tid & 63) == 0) {
            dstat[wid * 6 + 0] = sx;  dstat[wid * 6 + 1] = sy;  dstat[wid * 6 + 2] = sz;
            dstat[wid * 6 + 3] = qxx; dstat[wid * 6 + 4] = qyy; dstat[wid * 6 + 5] = qzz;
        }
        __syncthreads();
        if (tid == 0) {
            double* wd = (double*)(ws + WS_STAT);
            for (int qq = 0; qq < 6; qq++) {
                wd[b * 6 + qq] = dstat[qq] + dstat[6 + qq] + dstat[12 + qq] + dstat[18 + qq];
            }
        }
        __syncthreads();                         // ibuf free for append use
    }

    int wv = tid >> 6;                           // wave id: candidate quarter
    int lane = tid & 63;
    int i = chunk * QPB + lane;                  // this lane's query point
    float4 qp = pts[i];

    int cbase = wv * 1024;                       // this wave's candidate range

    // ---- seed: quarter's first 17 candidates straight into the list -------
    float md[KNN]; int mi[KNN];
#pragma unroll
    for (int k = 0; k < KNN; k++) {
        float4 c = pts[cbase + k];
        float dx = qp.x - c.x, dy = qp.y - c.y, dz = qp.z - c.z;
        md[k] = dx * dx + dy * dy + dz * dz;
        mi[k] = cbase + k;
    }
    float maxv = md[0]; int maxp = 0;
#pragma unroll
    for (int k = 1; k < KNN; k++) {
        bool g = md[k] > maxv;
        maxv = g ? md[k] : maxv;
        maxp = g ? k : maxp;
    }
    int cnt = 0;

    // ---- prologue: candidates 17..19 (align main loop to 4) ---------------
#pragma unroll
    for (int m = KNN; m < 20; m++) {
        float4 c = pts[cbase + m];
        float dx = qp.x - c.x, dy = qp.y - c.y, dz = qp.z - c.z;
        float d2 = dx * dx + dy * dy + dz * dz;
        if (d2 < maxv) {
            vbuf[cnt * BLKT + tid] = d2;
            ibuf[cnt * BLKT + tid] = cbase + m;
            cnt++;                               // cnt <= 3 here, no drain needed
        }
    }

    // ---- main scan: 4-candidate groups with register prefetch -------------
    float4 cc[4];
#pragma unroll
    for (int u = 0; u < 4; u++) cc[u] = pts[cbase + 20 + u];

    for (int m = 20; m < 1024; m += 4) {
        float4 cu[4];
#pragma unroll
        for (int u = 0; u < 4; u++) cu[u] = cc[u];
        int mn = (m + 4 < 1024) ? (m + 4) : 20;  // last prefetch redundant
#pragma unroll
        for (int u = 0; u < 4; u++) cc[u] = pts[cbase + mn + u];

#pragma unroll
        for (int u = 0; u < 4; u++) {
            float4 c = cu[u];
            float dx = qp.x - c.x, dy = qp.y - c.y, dz = qp.z - c.z;
            float d2 = dx * dx + dy * dy + dz * dz;   // self: exactly +0, kept
            if (d2 < maxv) {
                vbuf[cnt * BLKT + tid] = d2;
                ibuf[cnt * BLKT + tid] = cbase + m + u;
                cnt++;
            }
        }
        if (__any(cnt > CAP - 4)) {              // ensure room for next 4
            drain(vbuf, ibuf, tid, cnt, md, mi, maxv, maxp);
        }
    }
    drain(vbuf, ibuf, tid, cnt, md, mi, maxv, maxp);  // remainder

    // ---- 3-round LDS merge of the four quarter-lists into wave 0 ----------
    // publish: value-half in vbuf[lane*17+k], index-half in ibuf[lane*17+k]
    for (int r = 1; r < 4; r++) {
        __syncthreads();
        if (wv == r) {
#pragma unroll
            for (int k = 0; k < KNN; k++) {
                vbuf[lane * KNN + k] = md[k];
                ibuf[lane * KNN + k] = mi[k];
            }
        }
        __syncthreads();
        if (wv == 0) {
#pragma unroll
            for (int k = 0; k < KNN; k++) {
                float d = vbuf[lane * KNN + k];
                int ix = ibuf[lane * KNN + k];
                bool ins = d < maxv;
                if (__any(ins)) insertvi(d, ix, ins, md, mi, maxv, maxp);
            }
        }
    }

    // ---- epilogue on wave 0: moments -> curv, rasig2 ----------------------
    if (wv == 0) {
        float s1x = 0, s1y = 0, s1z = 0;
        float cxx = 0, cxy = 0, cxz = 0, cyy = 0, cyz = 0, czz = 0;
#pragma unroll
        for (int k = 0; k < KNN; k++) {
            float4 c = pts[mi[k]];
            float ux = c.x - qp.x, uy = c.y - qp.y, uz = c.z - qp.z;
            s1x += ux; s1y += uy; s1z += uz;
            cxx += ux * ux; cxy += ux * uy; cxz += ux * uz;
            cyy += uy * uy; cyz += uy * uz; czz += uz * uz;
        }
        const float i16 = 1.0f / 16.0f, i15 = 1.0f / 15.0f;
        float mx = s1x * i16, my = s1y * i16, mz = s1z * i16;
        float c00 = (cxx - 16.0f * mx * mx) * i15;
        float c01 = (cxy - 16.0f * mx * my) * i15;
        float c02 = (cxz - 16.0f * mx * mz) * i15;
        float c11 = (cyy - 16.0f * my * my) * i15;
        float c12 = (cyz - 16.0f * my * mz) * i15;
        float c22 = (czz - 16.0f * mz * mz) * i15;

        float curv = curv_from_cov(c00, c01, c02, c11, c12, c22);

        float v0 = c00 > 0.0f ? c00 : 0.0f;
        float v1 = c11 > 0.0f ? c11 : 0.0f;
        float v2 = c22 > 0.0f ? c22 : 0.0f;
        float r2x = 1.0f / (0.3f * (1.0f + sqrtf(v0)) + 1e-6f);
        float r2y = 1.0f / (0.3f * (1.0f + sqrtf(v1)) + 1e-6f);
        float r2z = 1.0f / (0.3f * (1.0f + sqrtf(v2)) + 1e-6f);

        int g = b * NPTS + i;
        ws[WS_CURV + g] = curv;
        ws[WS_RAS2 + 0 * 32768 + g] = r2x;
        ws[WS_RAS2 + 1 * 32768 + g] = r2y;
        ws[WS_RAS2 + 2 * 32768 + g] = r2z;

        float cs = curv;
        for (int off = 32; off > 0; off >>= 1) cs += __shfl_down(cs, off);
        if (lane == 0) atomicAdd(&ws[WS_CSUM + b], cs);
    }
}

// ---------------- final embedding ------------------------------------------
__global__ void out_kernel(const float* __restrict__ xyz,
                           const float* __restrict__ ws,
                           float* __restrict__ out) {
    int idx = blockIdx.x * 256 + (int)threadIdx.x;
    int j = idx & 127;
    int g = idx >> 7;
    int b = g >> 12;
    int f = (j < 127) ? j : 128;                      // OUT_IDX
    int d = (f >= 86) ? 2 : ((f >= 43) ? 1 : 0);
    int t = f - d * 43;
    float fv = (float)((double)(t + 1) * (2.0 / 44.0) - 1.0);  // FEAT_VAL[t]

    float x = xyz[g * 3 + d];
    float rasig1 = ws[WS_SCAL + 0];
    float blend  = ws[WS_SCAL + 1];
    float blendc = ws[WS_SCAL + 2];
    float cmean  = ws[WS_CSUM + b] * (1.0f / 4096.0f);
    float curv   = ws[WS_CURV + g];
    float w = 1.0f / (1.0f + __expf(-10.0f * (curv - cmean)));

    float t1 = (x - fv) * rasig1;
    float e1 = blend * __expf(-0.5f * t1 * t1) + blendc * __cosf(t1);
    float t2 = (x - fv) * ws[WS_RAS2 + (d << 15) + g];
    float e2 = __expf(-0.5f * t2 * t2);
    out[idx] = w * e1 + (1.0f - w) * e2;
}

extern "C" void kernel_launch(void* const* d_in, const int* in_sizes, int n_in,
                              void* d_out, int out_size, void* d_ws, size_t ws_size,
                              hipStream_t stream) {
    const float* xyz = (const float*)d_in[0];
    float* out = (float*)d_out;
    float* ws = (float*)d_ws;

    hipMemsetAsync(ws + WS_CSUM, 0, 8 * sizeof(float), stream);
    knn_kernel<<<512, BLKT, 0, stream>>>(xyz, ws);
    finalize_kernel<<<1, 64, 0, stream>>>(ws);
    out_kernel<<<out_size / 256, 256, 0, stream>>>(xyz, ws, out);
}